// Round 8
// baseline (194.236 us; speedup 1.0000x reference)
//
#include <hip/hip_runtime.h>

#define N_NODES 50000
#define N_EDGES 800000
#define IN_F    512
#define HEADS   8
#define DHEAD   32
#define NHD     256            // HEADS*DHEAD
#define SLOPE   0.2f
#define EPS_F   1e-16f
#define N_SBLK  ((N_NODES + 255) / 256)   // 196 scan blocks
#define NB_GEMM ((N_NODES + 63) / 64)     // 782 gemm blocks
#define NB_HIST ((N_EDGES + 4095) / 4096) // 196 hist blocks (4096 edges each)

typedef __attribute__((ext_vector_type(8))) short short8;
typedef __attribute__((ext_vector_type(4))) float f32x4;
typedef __attribute__((ext_vector_type(4))) unsigned short u16x4;

__device__ __forceinline__ unsigned short f2bf(float f) {
  unsigned int u = __float_as_uint(f);
  unsigned int r = u + 0x7FFFu + ((u >> 16) & 1u);   // round-to-nearest-even
  return (unsigned short)(r >> 16);
}
__device__ __forceinline__ float bf2f(unsigned short s) {
  return __uint_as_float(((unsigned int)s) << 16);
}

// ---- cast W -> WbT in MFMA-FRAGMENT order (bf16) + zero deg.
// chunk = (((k0s*2 + kk)*2 + wn2)*8 + j)*64 + lane  (16 B each):
//   c = wn2*128 + j*16 + (lane&15), q = kk*4 + (lane>>4), k = k0s*64 + q*8 + e
// so in the GEMM each fragment load is wave-uniform base + lane*16B (coalesced).
__global__ __launch_bounds__(256) void k_cast_w(const float* __restrict__ W,
                                                unsigned short* __restrict__ WbT,
                                                int* __restrict__ deg) {
  int id = blockIdx.x * 256 + threadIdx.x;       // 131072 elements
  int chunk = id >> 3, e = id & 7;
  int lane = chunk & 63;
  int t = chunk >> 6;
  int j = t & 7;  t >>= 3;
  int wn2 = t & 1; t >>= 1;
  int kk = t & 1;  t >>= 1;
  int k0s = t;                                   // 0..7
  int c = wn2 * 128 + j * 16 + (lane & 15);
  int k = k0s * 64 + (kk * 4 + (lane >> 4)) * 8 + e;
  WbT[id] = f2bf(W[(c >> 5) * (IN_F * DHEAD) + k * DHEAD + (c & 31)]);
  if (id < N_NODES) deg[id] = 0;
}

// ---- MFMA GEMM (blocks 0..781) + edge histogram (blocks 782..977).
// Tile 64(M)x256(N), 4 waves as 2M x 2N (wave = 32 rows x 128 cols).
// NO LDS, NO barriers: B fragments loaded coalesced from the fragment-packed
// WbT (256 KB, L2-resident); A loaded direct f32 + in-reg bf16 cast (2x
// redundancy across the wm pair -> L2 hit). Latency self-hidden per wave.
// Epilogue fuses s_src/s_dst score dots from f32 accumulators.
__global__ __launch_bounds__(256) void k_gemm_mfma(const float* __restrict__ x,
                                                   const unsigned short* __restrict__ WbT,
                                                   unsigned short* __restrict__ hb,
                                                   const float* __restrict__ a,
                                                   float* __restrict__ s_src,
                                                   float* __restrict__ s_dst,
                                                   const int* __restrict__ ei,
                                                   int* __restrict__ deg) {
  if (blockIdx.x >= NB_GEMM) {            // ---- histogram path (overlapped)
    int b = blockIdx.x - NB_GEMM;
    int end = min(b * 4096 + 4096, N_EDGES);
    for (int e = b * 4096 + threadIdx.x; e < end; e += 256)
      atomicAdd(&deg[ei[e]], 1);
    return;
  }

  const int tid  = threadIdx.x;
  const int lane = tid & 63;
  const int wid  = tid >> 6;
  const int wm   = wid >> 1;               // 0..1 (M half)
  const int wn2  = wid & 1;                // 0..1 (N half)
  const int bm   = blockIdx.x * 64;
  const int dl   = lane & 15;
  const int qg   = lane >> 4;              // 0..3

  // A row pointers (include lane's q-group byte offset qg*8 floats)
  const float* xr[2];
#pragma unroll
  for (int i = 0; i < 2; ++i)
    xr[i] = x + (size_t)min(bm + wm * 32 + i * 16 + dl, N_NODES - 1) * IN_F + qg * 8;

  f32x4 acc[2][8] = {};

#pragma unroll 2
  for (int k0s = 0; k0s < 8; ++k0s) {
#pragma unroll
    for (int kk = 0; kk < 2; ++kk) {
      // B: 8 coalesced 16B fragment loads (wave-uniform base + lane*16B)
      const unsigned short* bp =
          WbT + (((size_t)((k0s * 2 + kk) * 2 + wn2) * 8) * 64 + lane) * 8;
      short8 bfr[8];
#pragma unroll
      for (int j = 0; j < 8; ++j) bfr[j] = *(const short8*)(bp + (size_t)j * 64 * 8);
      // A: 2 fragments, f32 -> bf16 in-reg
      short8 af[2];
#pragma unroll
      for (int i = 0; i < 2; ++i) {
        const float* ap = xr[i] + k0s * 64 + kk * 32;
        float4 lo = *(const float4*)ap;
        float4 hi = *(const float4*)(ap + 4);
        short8 v;
        v[0] = (short)f2bf(lo.x); v[1] = (short)f2bf(lo.y);
        v[2] = (short)f2bf(lo.z); v[3] = (short)f2bf(lo.w);
        v[4] = (short)f2bf(hi.x); v[5] = (short)f2bf(hi.y);
        v[6] = (short)f2bf(hi.z); v[7] = (short)f2bf(hi.w);
        af[i] = v;
      }
#pragma unroll
      for (int i = 0; i < 2; ++i)
#pragma unroll
        for (int j = 0; j < 8; ++j)
          acc[i][j] = __builtin_amdgcn_mfma_f32_16x16x32_bf16(af[i], bfr[j], acc[i][j], 0, 0, 0);
    }
  }

  // ---- epilogue: hb (bf16) write + fused scores from f32 acc
  // C/D layout: col = wn2*128 + j*16 + dl, row = wm*32 + i*16 + qg*4 + q
  float as_[8], ad_[8];
#pragma unroll
  for (int j = 0; j < 8; ++j) {
    int hh = wn2 * 4 + (j >> 1);
    int d  = (j & 1) * 16 + dl;
    as_[j] = a[hh * 64 + d];
    ad_[j] = a[hh * 64 + 32 + d];
  }
#pragma unroll
  for (int i = 0; i < 2; ++i) {
#pragma unroll
    for (int q = 0; q < 4; ++q) {
      int row = bm + wm * 32 + i * 16 + qg * 4 + q;
      float ss[4] = {0.f, 0.f, 0.f, 0.f};
      float sd[4] = {0.f, 0.f, 0.f, 0.f};
#pragma unroll
      for (int j = 0; j < 8; ++j) {
        ss[j >> 1] += acc[i][j][q] * as_[j];
        sd[j >> 1] += acc[i][j][q] * ad_[j];
      }
#pragma unroll
      for (int o = 1; o < 16; o <<= 1) {
#pragma unroll
        for (int h2 = 0; h2 < 4; ++h2) {
          ss[h2] += __shfl_xor(ss[h2], o);
          sd[h2] += __shfl_xor(sd[h2], o);
        }
      }
      if (row < N_NODES) {
#pragma unroll
        for (int j = 0; j < 8; ++j)
          hb[(size_t)row * NHD + wn2 * 128 + j * 16 + dl] = f2bf(acc[i][j][q]);
        if (dl == 0) {
#pragma unroll
          for (int h2 = 0; h2 < 4; ++h2) {
            s_src[row * 8 + wn2 * 4 + h2] = ss[h2];
            s_dst[row * 8 + wn2 * 4 + h2] = sd[h2];
          }
        }
      }
    }
  }
}

// ---- CSR build: per-block degree sums (196 blocks x 256)
__global__ __launch_bounds__(256) void k_bsum(const int* __restrict__ deg,
                                              int* __restrict__ bsum) {
  __shared__ int sm[4];
  int i = blockIdx.x * 256 + threadIdx.x;
  int v = (i < N_NODES) ? deg[i] : 0;
#pragma unroll
  for (int o = 1; o < 64; o <<= 1) v += __shfl_xor(v, o);
  if ((threadIdx.x & 63) == 0) sm[threadIdx.x >> 6] = v;
  __syncthreads();
  if (threadIdx.x == 0) bsum[blockIdx.x] = sm[0] + sm[1] + sm[2] + sm[3];
}

// full scan: each block re-scans the 196 block sums, then its 256 degrees
__global__ __launch_bounds__(256) void k_scan_main(const int* __restrict__ deg,
                                                   const int* __restrict__ bsum,
                                                   int* __restrict__ rowptr,
                                                   int* __restrict__ cursor) {
  __shared__ int sb[256];
  __shared__ int sm[256];
  const int t = threadIdx.x;
  const int b = blockIdx.x;
  int bv = (t < N_SBLK) ? bsum[t] : 0;
  sb[t] = bv;
  int i = b * 256 + t;
  int v = (i < N_NODES) ? deg[i] : 0;
  sm[t] = v;
  __syncthreads();
#pragma unroll
  for (int o = 1; o < 256; o <<= 1) {
    int u1 = (t >= o) ? sb[t - o] : 0;
    int u2 = (t >= o) ? sm[t - o] : 0;
    __syncthreads();
    sb[t] += u1;
    sm[t] += u2;
    __syncthreads();
  }
  int boff = (b > 0) ? sb[b - 1] : 0;
  if (i < N_NODES) {
    int ex = boff + sm[t] - v;
    rowptr[i] = ex;
    cursor[i] = ex;
  }
  if (b == 0 && t == 0) rowptr[N_NODES] = sb[255];
}

__global__ void k_fill(const int* __restrict__ ei, int* __restrict__ cursor,
                       int* __restrict__ edst) {
  int e = blockIdx.x * blockDim.x + threadIdx.x;
  if (e >= N_EDGES) return;
  int p = atomicAdd(&cursor[ei[e]], 1);
  edst[p] = ei[N_EDGES + e];
}

// ---- fused aggregation: one wave per node, m=0 softmax, 2-way unrolled
__global__ __launch_bounds__(256) void k_aggr(const int* __restrict__ rowptr,
                                              const int* __restrict__ edst,
                                              const float* __restrict__ s_src,
                                              const float* __restrict__ s_dst,
                                              const unsigned short* __restrict__ hb,
                                              float* __restrict__ out) {
  int n = (int)((blockIdx.x * blockDim.x + threadIdx.x) >> 6);
  if (n >= N_NODES) return;
  n = __builtin_amdgcn_readfirstlane(n);
  const int lane = threadIdx.x & 63;
  const int head = lane >> 3;
  const float ssrc = s_src[n * 8 + head];
  int i = rowptr[n];
  const int iend = rowptr[n + 1];
  float den = 0.f;
  f32x4 acc = {0.f, 0.f, 0.f, 0.f};
  for (; i + 1 < iend; i += 2) {
    int d0 = edst[i], d1 = edst[i + 1];
    float v0 = ssrc + s_dst[d0 * 8 + head];
    float v1 = ssrc + s_dst[d1 * 8 + head];
    u16x4 h0 = *(const u16x4*)(hb + (size_t)d0 * NHD + lane * 4);
    u16x4 h1 = *(const u16x4*)(hb + (size_t)d1 * NHD + lane * 4);
    v0 = v0 >= 0.f ? v0 : SLOPE * v0;
    v1 = v1 >= 0.f ? v1 : SLOPE * v1;
    float e0 = __expf(v0), e1 = __expf(v1);
    den += e0 + e1;
    acc.x += e0 * bf2f(h0.x) + e1 * bf2f(h1.x);
    acc.y += e0 * bf2f(h0.y) + e1 * bf2f(h1.y);
    acc.z += e0 * bf2f(h0.z) + e1 * bf2f(h1.z);
    acc.w += e0 * bf2f(h0.w) + e1 * bf2f(h1.w);
  }
  if (i < iend) {
    int d0 = edst[i];
    float v0 = ssrc + s_dst[d0 * 8 + head];
    v0 = v0 >= 0.f ? v0 : SLOPE * v0;
    float e0 = __expf(v0);
    u16x4 h0 = *(const u16x4*)(hb + (size_t)d0 * NHD + lane * 4);
    den += e0;
    acc.x += e0 * bf2f(h0.x);
    acc.y += e0 * bf2f(h0.y);
    acc.z += e0 * bf2f(h0.z);
    acc.w += e0 * bf2f(h0.w);
  }
  float inv = 1.f / (den + EPS_F);         // deg==0: acc=0 -> out=0
  *(f32x4*)(out + (size_t)n * NHD + lane * 4) = acc * inv;
}

extern "C" void kernel_launch(void* const* d_in, const int* in_sizes, int n_in,
                              void* d_out, int out_size, void* d_ws, size_t ws_size,
                              hipStream_t stream) {
  const float* x  = (const float*)d_in[0];
  const int*   ei = (const int*)d_in[1];
  const float* W  = (const float*)d_in[2];
  const float* a  = (const float*)d_in[3];
  float* out = (float*)d_out;

  // workspace layout (~33 MB, 16B-aligned blocks)
  unsigned short* hb  = (unsigned short*)d_ws;                 // 12,800,000 u16
  unsigned short* WbT = hb + (size_t)N_NODES * NHD;            // 131,072 u16 (fragment-packed)
  float* s_src = (float*)(WbT + (size_t)NHD * IN_F);           // 400,000 f
  float* s_dst = s_src + (size_t)N_NODES * HEADS;              // 400,000 f
  int* deg    = (int*)(s_dst + (size_t)N_NODES * HEADS);       // 50,000
  int* cursor = deg + N_NODES;                                 // 50,000
  int* rowptr = cursor + N_NODES;                              // 50,001 (pad 50,008)
  int* bsum   = rowptr + 50008;                                // 196 (pad 256)
  int* edst   = bsum + 256;                                    // 800,000

  k_cast_w<<<512, 256, 0, stream>>>(W, WbT, deg);
  k_gemm_mfma<<<NB_GEMM + NB_HIST, 256, 0, stream>>>(x, WbT, hb, a, s_src, s_dst, ei, deg);
  k_bsum<<<N_SBLK, 256, 0, stream>>>(deg, bsum);
  k_scan_main<<<N_SBLK, 256, 0, stream>>>(deg, bsum, rowptr, cursor);
  k_fill<<<(N_EDGES + 255) / 256, 256, 0, stream>>>(ei, cursor, edst);
  k_aggr<<<(N_NODES * 64 + 255) / 256, 256, 0, stream>>>(rowptr, edst, s_src, s_dst, hb, out);
}